// Round 7
// baseline (147.551 us; speedup 1.0000x reference)
//
#include <hip/hip_runtime.h>
#include <cstdint>

#define N_ANCH 8400
#define CBLK 132              // ceil(8400/64)
#define SCORE_THR 0.5f

typedef unsigned long long u64;
typedef unsigned int u32;

// Sort key: ascending sort == (valid score descending, then index ascending,
// invalid last by index ascending) — exactly matches
// argsort(-where(valid, s, -inf)) with stable ties.
__device__ __forceinline__ u64 sort_key(float s, int idx) {
  u32 k32 = (s >= SCORE_THR) ? ~__float_as_uint(s) : 0xFFFFFFFFu;
  return ((u64)k32 << 32) | (u32)idx;
}

// Force a wave-uniform u64 into SGPRs.
__device__ __forceinline__ u64 rfl64(u64 v) {
  u32 lo = (u32)__builtin_amdgcn_readfirstlane((int)(u32)v);
  u32 hi = (u32)__builtin_amdgcn_readfirstlane((int)(u32)(v >> 32));
  return ((u64)hi << 32) | lo;
}

// One 64-lane wave per anchor: rank = #{keys smaller}, then scatter
// decoded box + score into sorted position.
__global__ void __launch_bounds__(256) rank_kernel(const float* __restrict__ raw,
                                                   float4* __restrict__ sbox,
                                                   float* __restrict__ sscore) {
  #pragma clang fp contract(off)
  int tid = blockIdx.x * 256 + threadIdx.x;
  int row = tid >> 6, lane = tid & 63;
  if (row >= N_ANCH) return;
  float si = raw[4 * N_ANCH + row];
  u64 ki = sort_key(si, row);
  int cnt = 0;
  for (int j = lane; j < N_ANCH; j += 64) {
    float sj = raw[4 * N_ANCH + j];
    cnt += (sort_key(sj, j) < ki) ? 1 : 0;
  }
  #pragma unroll
  for (int d = 1; d < 64; d <<= 1) cnt += __shfl_xor(cnt, d, 64);
  if (lane == 0) {
    float cx = raw[row], cy = raw[N_ANCH + row];
    float w = raw[2 * N_ANCH + row], h = raw[3 * N_ANCH + row];
    float hw = w * 0.5f, hh = h * 0.5f;
    sbox[cnt] = make_float4(cx - hw, cy - hh, cx + hw, cy + hh);
    sscore[cnt] = si;
  }
}

// Suppression bitmask, two output layouts:
//   ABOVE diagonal (cb > i>>6): wHi (row word, "boxes I suppress") stored
//     row-major in mask[i*CBLK+cb]. Read by nms consume tiles (coalesced:
//     lane = col).
//   NEAR/BELOW diagonal (0 <= d = (i>>6)-cb <= 5): wLo (COLUMN word,
//     "boxes that suppress me") stored TRANSPOSED in
//     wlo_t[d][i>>6][i&63] — contiguous in lane. nms wave0 reads these
//     11x/iter; the old row-major layout made each such read touch 64
//     cache lines (stride 1056 B); this layout makes it 4 lines (512 B
//     contiguous) — a 16x cut in L1/TCP line traffic on the pacing wave.
//   d > 5: dead, nothing written (band skip at block granularity).
__global__ void __launch_bounds__(256) mask_kernel(const float4* __restrict__ sbox,
                                                   const float* __restrict__ sscore,
                                                   u64* __restrict__ mask,
                                                   u64* __restrict__ wlo_t) {
  #pragma clang fp contract(off)
  int cb = blockIdx.x;
  int i0 = blockIdx.y * 256;
  if (cb + 5 < (i0 >> 6)) return;                // below-diagonal band skip
  if (!(sscore[i0] >= SCORE_THR)) return;        // whole row-block invalid
  if (!(sscore[cb * 64] >= SCORE_THR)) return;   // whole col-block invalid
  int t = threadIdx.x;
  __shared__ float4 cbox[64];
  __shared__ float carea[64];
  int j0 = cb * 64;
  if (t < 64) {
    int j = j0 + t;
    float4 bj = (j < N_ANCH) ? sbox[j] : make_float4(0.f, 0.f, 0.f, 0.f);
    cbox[t] = bj;
    carea[t] = (bj.z - bj.x) * (bj.w - bj.y);
  }
  __syncthreads();
  int i = i0 + t;
  if (i >= N_ANCH) return;
  float4 bi = sbox[i];
  float ai = (bi.z - bi.x) * (bi.w - bi.y);
  u64 wHi = 0, wLo = 0;
  for (int jj = 0; jj < 64; ++jj) {
    int jg = j0 + jj;
    float4 bb = cbox[jj];
    float ltx = fmaxf(bi.x, bb.x), lty = fmaxf(bi.y, bb.y);
    float rbx = fminf(bi.z, bb.z), rby = fminf(bi.w, bb.w);
    float wx = fmaxf(rbx - ltx, 0.f), wy = fmaxf(rby - lty, 0.f);
    float inter = wx * wy;
    float uni = (ai + carea[jj]) - inter;      // same op order as reference
    float iou = inter / fmaxf(uni, 1e-9f);     // IEEE div, matches numpy
    bool sup = (iou > 0.5f) && (jg < N_ANCH);
    wHi |= (u64)(sup && (jg > i)) << jj;
    wLo |= (u64)(sup && (jg < i)) << jj;
  }
  int rb = i >> 6;
  int d = rb - cb;
  if (d < 0) {
    mask[(u64)i * CBLK + cb] = wHi;              // row word, above diagonal
  } else if (d <= 5) {
    wlo_t[((u64)d * CBLK + rb) * 64 + (i & 63)] = wLo;  // transposed col word
  }
}

// PIPELINED NMS with KEEPER-FILTERED lag-2 consume (R6 schedule, unchanged)
// + COALESCED wave-0 column-word loads from wlo_t (this round's change).
//
// Wave 0 scans words 2T,2T+1 at iter T (ballot fixpoint). Consume waves
// (1-7) issue tile loads ONLY for keeper rows (keepw[2(T-1)] published at
// T-1), consume them at T+1. Pipeline coverage (word W=2u affects col c>W):
// c=W in-scan (cA); c=W+1 coupling ballot (cB); c=W+2..W+5 wave0 register
// carries (4 ballots, lag-1 pair p0/p1 + lag-2 pair q0/q1); c>=W+6 consume
// tiles, L-half [W+6,W+70) + H-half [W+70,W+134) — covers VB<=132.
// Consume at iter X writes cols >= 2X+2, never racing wave0's rem reads;
// keepw writes never race consume's lagged keepw reads. Barriers drain LDS
// ONLY (lgkmcnt) — global prefetches stay in flight across them.
__global__ void __launch_bounds__(512, 1) nms_kernel(const float4* __restrict__ sbox,
                                                     const float* __restrict__ sscore,
                                                     const u64* __restrict__ mask,
                                                     const u64* __restrict__ wlo_t,
                                                     float* __restrict__ out) {
  __shared__ u64 keepw[CBLK + 2];                // +2: b1==VB==132 tail write
  __shared__ u64 rem[CBLK + 2];
  int tid = threadIdx.x;
  int wave = tid >> 6, lane = tid & 63;

  // ---- n_valid via 2-round probe (redundant in every wave — same result)
  float s0 = sscore[lane * 132];                 // 63*132 = 8316 < 8400
  u64 pb = __ballot(s0 >= SCORE_THR);
  int cnt1 = (int)__popcll(pb);
  int n_valid = 0;
  if (cnt1 > 0) {
    int a = (cnt1 - 1) * 132 + 1;                // rows < a known valid
    int i1 = a + 3 * lane;
    float t1 = (i1 + 0 < N_ANCH) ? sscore[i1 + 0] : -1.f;
    float t2 = (i1 + 1 < N_ANCH) ? sscore[i1 + 1] : -1.f;
    float t3 = (i1 + 2 < N_ANCH) ? sscore[i1 + 2] : -1.f;
    u64 q1 = __ballot(t1 >= SCORE_THR);
    u64 q2 = __ballot(t2 >= SCORE_THR);
    u64 q3 = __ballot(t3 >= SCORE_THR);
    n_valid = a + (int)__popcll(q1) + (int)__popcll(q2) + (int)__popcll(q3);
  }
  int VB = (n_valid + 63) >> 6;                  // number of valid 64-blocks
  int NT = (VB + 1) >> 1;                        // 128-row iterations

  for (int b = tid; b < CBLK + 2; b += 512) { keepw[b] = 0; rem[b] = 0; }

  // ---- consume-wave state (waves 1..7): rows split 19x6 + 14
  int rs = (wave - 1) * 19;                      // row start within 128-pair
  int nr = 128 - rs; if (nr > 19) nr = 19;       // rows this wave owns
  u64 tl[19], th[19];                            // keeper-filtered tiles

  // ---- wave-0 state: transposed column words, double-buffered. Lane i:
  //   cA  = wlo_t[0][b0]   (box-block b0 vs rows b0, diag)
  //   cB  = wlo_t[1][b1]   (box-block b1 vs rows b0)
  //   cC  = wlo_t[0][b1]   (diag)
  //   cD0/cD1 = wlo_t[2]/[1] [b0+2]   (vs rows b0/b1)
  //   cE0/cE1 = wlo_t[3]/[2] [b0+3]
  //   cF0/cF1 = wlo_t[4]/[3] [b0+4]
  //   cG0/cG1 = wlo_t[5]/[4] [b0+5]
  // All 11 loads are 512-B contiguous (lane-indexed) — 4 lines each.
  u64 cA=0,cB=0,cC=0,cD0=0,cD1=0,cE0=0,cE1=0,cF0=0,cF1=0,cG0=0,cG1=0;
  u64 nA=0,nB=0,nC=0,nD0=0,nD1=0,nE0=0,nE1=0,nF0=0,nF1=0,nG0=0,nG1=0;
  auto wt = [&](int d, int b) -> u64 {
    return wlo_t[((u64)d * CBLK + b) * 64 + lane];
  };
  auto load_w0 = [&](int T2, u64&A,u64&B,u64&C,u64&D0,u64&D1,u64&E0,u64&E1,
                     u64&F0,u64&F1,u64&G0,u64&G1) {
    int b0 = 2 * T2, b1 = b0 + 1;
    bool ok1 = (b1 < VB), ok2 = (b0 + 2 < VB), ok3 = (b0 + 3 < VB);
    bool ok4 = (b0 + 4 < VB), ok5 = (b0 + 5 < VB);
    A  = wt(0, b0);
    B  = ok1 ? wt(1, b1) : 0ull;
    C  = ok1 ? wt(0, b1) : 0ull;
    D0 = ok2 ? wt(2, b0 + 2) : 0ull;  D1 = ok2 ? wt(1, b0 + 2) : 0ull;
    E0 = ok3 ? wt(3, b0 + 3) : 0ull;  E1 = ok3 ? wt(2, b0 + 3) : 0ull;
    F0 = ok4 ? wt(4, b0 + 4) : 0ull;  F1 = ok4 ? wt(3, b0 + 4) : 0ull;
    G0 = ok5 ? wt(5, b0 + 5) : 0ull;  G1 = ok5 ? wt(4, b0 + 5) : 0ull;
  };

  u64 p0c = 0, p1c = 0;                          // lag-1 carry -> cols 2T,2T+1
  u64 q0c = 0, q1c = 0;                          // lag-2 carry -> cols 2T,2T+1
  u64 qn0 = 0, qn1 = 0;                          // staging for next lag-2

  if (wave == 0 && NT > 0)
    load_w0(0, cA,cB,cC,cD0,cD1,cE0,cE1,cF0,cF1,cG0,cG1);

  for (int T = 0; T < NT; ++T) {
    // one barrier per iteration; LDS-only drain — global loads stay in flight
    asm volatile("s_waitcnt lgkmcnt(0)\ns_barrier" ::: "memory");

    if (wave == 0) {
      __builtin_amdgcn_s_setprio(1);             // favor the serial scan wave
      int b0 = 2 * T, b1 = b0 + 1;
      u64 rb0 = rem[b0], rb1 = rem[b1];          // issue ds_reads early
      // rotate double buffer; issue next iteration's 11 loads immediately
      if (T > 0) { cA=nA; cB=nB; cC=nC; cD0=nD0; cD1=nD1; cE0=nE0; cE1=nE1;
                   cF0=nF0; cF1=nF1; cG0=nG0; cG1=nG1; }
      if (T + 1 < NT)
        load_w0(T + 1, nA,nB,nC,nD0,nD1,nE0,nE1,nF0,nF1,nG0,nG1);

      u64 remb0 = rfl64(rb0) | p0c | q0c;        // carries already SGPR
      u64 remb1 = rfl64(rb1) | p1c | q1c;
      int remn0 = n_valid - b0 * 64;             // >= 1
      int remn1 = remn0 - 64;
      u64 vm0 = (remn0 >= 64) ? ~0ull : ((1ull << remn0) - 1ull);
      u64 vm1 = (remn1 >= 64) ? ~0ull
              : ((remn1 <= 0) ? 0ull : ((1ull << remn1) - 1ull));
      u64 act0 = vm0 & ~remb0;                   // SGPR
      u64 act1 = vm1 & ~remb1;                   // SGPR

      // ---- word0: ballot-round greedy fixpoint
      u64 U = act0, K0 = 0;
      while (U) {
        u64 covered = __ballot((cA & U) != 0ull);
        u64 nk = U & ~covered;                   // definite keepers
        u64 supp = __ballot((cA & nk) != 0ull);  // definitely suppressed
        K0 |= nk;
        U &= ~(nk | supp);
      }
      u64 kw0 = K0;

      // ---- word1: remove word0-keeper suppression (one ballot), then scan
      u64 s01 = __ballot((cB & kw0) != 0ull);
      u64 U1 = act1 & ~s01, K1 = 0;
      while (U1) {
        u64 covered = __ballot((cC & U1) != 0ull);
        u64 nk = U1 & ~covered;
        u64 supp = __ballot((cC & nk) != 0ull);
        K1 |= nk;
        U1 &= ~(nk | supp);
      }
      u64 kw1 = K1;

      if (lane == 0) { keepw[b0] = kw0; keepw[b1] = kw1; }

      // ---- carries: words b0,b1 -> cols b0+2..b0+5 (4 ballots)
      u64 f2 = __ballot(((cD0 & kw0) | (cD1 & kw1)) != 0ull);
      u64 f3 = __ballot(((cE0 & kw0) | (cE1 & kw1)) != 0ull);
      u64 f4 = __ballot(((cF0 & kw0) | (cF1 & kw1)) != 0ull);
      u64 f5 = __ballot(((cG0 & kw0) | (cG1 & kw1)) != 0ull);
      p0c = f2; p1c = f3;                        // land at T+1
      q0c = qn0; q1c = qn1;                      // land at T+1 (from T-1)
      qn0 = f4; qn1 = f5;                        // land at T+2
      __builtin_amdgcn_s_setprio(0);             // yield while others consume
    } else {
      // ---- consume tiles issued at T-1 (word-pair 2(T-2)), keeper-filtered
      // at load time — OR loop is mask-free (non-keeper rows loaded as 0).
      if (T >= 2) {
        int u = T - 2;
        int base = 2 * u + 6;
        if (base < VB) {
          u64 acc = 0;
          #pragma unroll
          for (int r = 0; r < 19; ++r) acc |= tl[r];
          int cL = base + lane;
          if (cL < VB && acc) atomicOr((unsigned long long*)&rem[cL], acc);
          if (base + 64 < VB) {                  // H half exists at all?
            u64 acc2 = 0;
            #pragma unroll
            for (int r = 0; r < 19; ++r) acc2 |= th[r];
            int cH = base + 64 + lane;
            if (cH < VB && acc2) atomicOr((unsigned long long*)&rem[cH], acc2);
          }
        }
      }
      // ---- issue keeper-filtered tiles for word-pair 2(T-1); keepw was
      // published at iter T-1, read post-barrier. Consumed at T+1.
      if (T >= 1 && T + 1 < NT) {
        int u = T - 1;
        int base = 2 * u + 6;
        if (base < VB) {
          u64 kws0 = rfl64(keepw[2 * u]);        // broadcast read
          u64 kws1 = rfl64(keepw[2 * u + 1]);
          int cL = base + lane;
          bool okL = (cL < VB);
          // rows 128u+rs..+18: u <= NT-3 -> row <= 128*(NT-3)+127 < 8400
          const u64* pr = mask + (u64)(128 * u + rs) * CBLK;
          #pragma unroll
          for (int r = 0; r < 19; ++r) {
            int rr = rs + r;                     // wave-uniform
            u64 kb = (rr < 64) ? (kws0 >> rr) : (kws1 >> (rr - 64));
            bool rok = (r < nr) && ((kb & 1ull) != 0ull);
            tl[r] = (rok && okL) ? pr[(u64)r * CBLK + cL] : 0ull;
          }
          if (base + 64 < VB) {
            int cH = cL + 64;
            bool okH = (cH < VB);
            #pragma unroll
            for (int r = 0; r < 19; ++r) {
              int rr = rs + r;
              u64 kb = (rr < 64) ? (kws0 >> rr) : (kws1 >> (rr - 64));
              bool rok = (r < nr) && ((kb & 1ull) != 0ull);
              th[r] = (rok && okH) ? pr[(u64)r * CBLK + cH] : 0ull;
            }
          }
        }
      }
    }
  }
  __syncthreads();

  // ---- fused masked output (512 threads)
  for (int r2 = tid; r2 < N_ANCH; r2 += 512) {
    u64 kv = keepw[r2 >> 6];
    bool kp = (kv >> (r2 & 63)) & 1ull;
    float4 b4 = sbox[r2];
    float sc = sscore[r2];
    float* o = out + r2 * 5;
    o[0] = kp ? b4.x : 0.f;
    o[1] = kp ? b4.y : 0.f;
    o[2] = kp ? b4.z : 0.f;
    o[3] = kp ? b4.w : 0.f;
    o[4] = kp ? sc : 0.f;
  }
}

extern "C" void kernel_launch(void* const* d_in, const int* in_sizes, int n_in,
                              void* d_out, int out_size, void* d_ws, size_t ws_size,
                              hipStream_t stream) {
  const float* raw = (const float*)d_in[0];
  float* out = (float*)d_out;
  char* ws = (char*)d_ws;
  // ws layout: sbox (8448*16 B) | sscore (8448*4 B) | mask (8400*132*8 B)
  //          | wlo_t (6*132*64*8 B)  ≈ 9.45 MB total
  float4* sbox = (float4*)ws;
  float* sscore = (float*)(ws + 8448 * 16);
  u64* mask = (u64*)(ws + 8448 * 16 + 8448 * 4);
  u64* wlo_t = (u64*)(ws + 8448 * 16 + 8448 * 4 + (size_t)N_ANCH * CBLK * 8);

  rank_kernel<<<2100, 256, 0, stream>>>(raw, sbox, sscore);
  mask_kernel<<<dim3(CBLK, 33), 256, 0, stream>>>(sbox, sscore, mask, wlo_t);
  nms_kernel<<<1, 512, 0, stream>>>(sbox, sscore, mask, wlo_t, out);
}

// Round 8
// 131.592 us; speedup vs baseline: 1.1213x; 1.1213x over previous
//
#include <hip/hip_runtime.h>
#include <cstdint>

#define N_ANCH 8400
#define CBLK 132              // ceil(8400/64)
#define SCORE_THR 0.5f
#define NDIAG 8               // wlo_t diagonals 0..7

typedef unsigned long long u64;
typedef unsigned int u32;

// Sort key: ascending sort == (valid score descending, then index ascending,
// invalid last by index ascending) — exactly matches
// argsort(-where(valid, s, -inf)) with stable ties.
__device__ __forceinline__ u64 sort_key(float s, int idx) {
  u32 k32 = (s >= SCORE_THR) ? ~__float_as_uint(s) : 0xFFFFFFFFu;
  return ((u64)k32 << 32) | (u32)idx;
}

// Force a wave-uniform u64 into SGPRs.
__device__ __forceinline__ u64 rfl64(u64 v) {
  u32 lo = (u32)__builtin_amdgcn_readfirstlane((int)(u32)v);
  u32 hi = (u32)__builtin_amdgcn_readfirstlane((int)(u32)(v >> 32));
  return ((u64)hi << 32) | lo;
}

// 4 rows per wave: one pass over the score array serves 4 rank counts.
// 2100 waves (vs 8400) — 4x fewer score loads, ~2.5x less VALU.
__global__ void __launch_bounds__(256) rank_kernel(const float* __restrict__ raw,
                                                   float4* __restrict__ sbox,
                                                   float* __restrict__ sscore) {
  #pragma clang fp contract(off)
  int tid = blockIdx.x * 256 + threadIdx.x;
  int wid = tid >> 6, lane = tid & 63;
  int base = wid * 4;                            // 525 blocks -> base <= 8396
  float sl = raw[4 * N_ANCH + base + (lane & 3)];
  float s0 = __shfl(sl, 0), s1 = __shfl(sl, 1);
  float s2 = __shfl(sl, 2), s3 = __shfl(sl, 3);
  u64 k0 = sort_key(s0, base),     k1 = sort_key(s1, base + 1);
  u64 k2 = sort_key(s2, base + 2), k3 = sort_key(s3, base + 3);
  int c0 = 0, c1 = 0, c2 = 0, c3 = 0;
  #pragma unroll 2
  for (int j = lane; j < N_ANCH; j += 64) {
    float sj = raw[4 * N_ANCH + j];
    u64 kj = sort_key(sj, j);
    c0 += kj < k0; c1 += kj < k1; c2 += kj < k2; c3 += kj < k3;
  }
  #pragma unroll
  for (int d = 1; d < 64; d <<= 1) {
    c0 += __shfl_xor(c0, d, 64); c1 += __shfl_xor(c1, d, 64);
    c2 += __shfl_xor(c2, d, 64); c3 += __shfl_xor(c3, d, 64);
  }
  if (lane < 4) {
    int row = base + lane;
    int cnt = (lane == 0) ? c0 : (lane == 1) ? c1 : (lane == 2) ? c2 : c3;
    float sc = (lane == 0) ? s0 : (lane == 1) ? s1 : (lane == 2) ? s2 : s3;
    float cx = raw[row], cy = raw[N_ANCH + row];
    float w = raw[2 * N_ANCH + row], h = raw[3 * N_ANCH + row];
    float hw = w * 0.5f, hh = h * 0.5f;
    sbox[cnt] = make_float4(cx - hw, cy - hh, cx + hw, cy + hh);
    sscore[cnt] = sc;
  }
}

// Suppression bitmask, two output layouts:
//   ABOVE diagonal (cb > i>>6): wHi (row word, "boxes I suppress") in
//     mask[i*CBLK+cb]. Read by nms consume tiles (distance >= 5 only).
//   NEAR diagonal (0 <= d = (i>>6)-cb <= 7): wLo (COLUMN word, "boxes that
//     suppress me") TRANSPOSED in wlo_t[d][i>>6][i&63] — contiguous in
//     lane, so nms wave0's reads touch 4 cache lines, not 64.
//   d > 7: dead (band skip).
__global__ void __launch_bounds__(256) mask_kernel(const float4* __restrict__ sbox,
                                                   const float* __restrict__ sscore,
                                                   u64* __restrict__ mask,
                                                   u64* __restrict__ wlo_t) {
  #pragma clang fp contract(off)
  int cb = blockIdx.x;
  int i0 = blockIdx.y * 256;
  if (cb + 7 < (i0 >> 6)) return;                // below-diagonal band skip
  if (!(sscore[i0] >= SCORE_THR)) return;        // whole row-block invalid
  if (!(sscore[cb * 64] >= SCORE_THR)) return;   // whole col-block invalid
  int t = threadIdx.x;
  __shared__ float4 cbox[64];
  __shared__ float carea[64];
  int j0 = cb * 64;
  if (t < 64) {
    int j = j0 + t;
    float4 bj = (j < N_ANCH) ? sbox[j] : make_float4(0.f, 0.f, 0.f, 0.f);
    cbox[t] = bj;
    carea[t] = (bj.z - bj.x) * (bj.w - bj.y);
  }
  __syncthreads();
  int i = i0 + t;
  if (i >= N_ANCH) return;
  float4 bi = sbox[i];
  float ai = (bi.z - bi.x) * (bi.w - bi.y);
  u64 wHi = 0, wLo = 0;
  for (int jj = 0; jj < 64; ++jj) {
    int jg = j0 + jj;
    float4 bb = cbox[jj];
    float ltx = fmaxf(bi.x, bb.x), lty = fmaxf(bi.y, bb.y);
    float rbx = fminf(bi.z, bb.z), rby = fminf(bi.w, bb.w);
    float wx = fmaxf(rbx - ltx, 0.f), wy = fmaxf(rby - lty, 0.f);
    float inter = wx * wy;
    float uni = (ai + carea[jj]) - inter;      // same op order as reference
    float iou = inter / fmaxf(uni, 1e-9f);     // IEEE div, matches numpy
    bool sup = (iou > 0.5f) && (jg < N_ANCH);
    wHi |= (u64)(sup && (jg > i)) << jj;
    wLo |= (u64)(sup && (jg < i)) << jj;
  }
  int rb = i >> 6;
  int d = rb - cb;
  if (d < 0) {
    mask[(u64)i * CBLK + cb] = wHi;              // row word, above diagonal
  } else if (d < NDIAG) {
    wlo_t[((u64)d * CBLK + rb) * 64 + (i & 63)] = wLo;  // transposed col word
  }
}

// PIPELINED NMS, 4 WORDS (256 rows) PER ITERATION — amortizes the fixed
// per-iteration cost (barrier, LDS round trips, vmcnt rotate) over 2x the
// rows (NT 33 -> 17). Wave 0 scans words 4g..4g+3 (ballot fixpoints with
// in-register coupling); waves 1-7 same-iteration keeper-filtered consume.
//
// Coverage of pair (w, c), w < c < VB (disjoint, exhaustive):
//   c == w           : within-word fixpoint (diag col word, d=0)
//   c-w in 1..3 (grp): coupling ballots s1/s2/s3 over wlo_t d=1..3
//   c in 4g+4..4g+7  : carry bank P[4] — ballots over wlo_t d=1..7,
//                      landing at iter g+1 (rem for cols 4(g+1)..+3)
//   c >= 4g+8        : consume at iter g+1 — keepw[4g..4g+3] read
//                      post-barrier, keeper rows' mask words loaded,
//                      vmcnt-waited, OR'd, ds_or'd into rem — all within
//                      the iteration (slack = wave0's scan).
// Races: consume at iter X writes rem[c >= 4X+4]; wave0 reads rem[4X..4X+3]
// — disjoint. keepw written by wave0 at g, read by consume at g+1 (barrier
// between). Barriers drain LDS only (lgkmcnt) — globals stay in flight.
__global__ void __launch_bounds__(512, 1) nms_kernel(const float4* __restrict__ sbox,
                                                     const float* __restrict__ sscore,
                                                     const u64* __restrict__ mask,
                                                     const u64* __restrict__ wlo_t,
                                                     float* __restrict__ out) {
  __shared__ u64 keepw[CBLK + 4];
  __shared__ u64 rem[CBLK + 4];
  int tid = threadIdx.x;
  int wave = tid >> 6, lane = tid & 63;

  // ---- n_valid via 2-round probe (redundant in every wave — same result)
  float s0 = sscore[lane * 132];                 // 63*132 = 8316 < 8400
  u64 pb = __ballot(s0 >= SCORE_THR);
  int cnt1 = (int)__popcll(pb);
  int n_valid = 0;
  if (cnt1 > 0) {
    int a = (cnt1 - 1) * 132 + 1;                // rows < a known valid
    int i1 = a + 3 * lane;
    float t1 = (i1 + 0 < N_ANCH) ? sscore[i1 + 0] : -1.f;
    float t2 = (i1 + 1 < N_ANCH) ? sscore[i1 + 1] : -1.f;
    float t3 = (i1 + 2 < N_ANCH) ? sscore[i1 + 2] : -1.f;
    u64 q1 = __ballot(t1 >= SCORE_THR);
    u64 q2 = __ballot(t2 >= SCORE_THR);
    u64 q3 = __ballot(t3 >= SCORE_THR);
    n_valid = a + (int)__popcll(q1) + (int)__popcll(q2) + (int)__popcll(q3);
  }
  int VB = (n_valid + 63) >> 6;                  // number of valid 64-blocks
  int NG = (VB + 3) >> 2;                        // 256-row iterations

  for (int b = tid; b < CBLK + 4; b += 512) { keepw[b] = 0; rem[b] = 0; }

  // ---- consume-wave row split: 7 waves x 37 rows (last 34) of each 256-row group
  int rs = (wave - 1) * 37;
  int nr = 256 - rs; if (nr > 37) nr = 37;

  // ---- wave-0 load set per group (26 u64, all coalesced wlo_t reads):
  //  [0..3]  A_k  = wt(0, 4g+k)         scan diag
  //  [4]     C10=wt(1,4g+1)  [5] C20=wt(2,4g+2)  [6] C21=wt(1,4g+2)
  //  [7]     C30=wt(3,4g+3)  [8] C31=wt(2,4g+3)  [9] C32=wt(1,4g+3)
  //  [10+4m+j] X[m][j] = wt(4+m-j, 4g+4+m)   carries to cols 4g+4..4g+7
  u64 cur[26], nxt[26];
  auto wt = [&](int d, int b) -> u64 {
    return wlo_t[((u64)d * CBLK + b) * 64 + lane];
  };
  auto load_w0 = [&](int g, u64* R) {
    int b = 4 * g;                               // b < VB guaranteed by caller
    bool k1 = (b + 1 < VB), k2 = (b + 2 < VB), k3 = (b + 3 < VB);
    R[0] = wt(0, b);
    R[1] = k1 ? wt(0, b + 1) : 0ull;
    R[2] = k2 ? wt(0, b + 2) : 0ull;
    R[3] = k3 ? wt(0, b + 3) : 0ull;
    R[4] = k1 ? wt(1, b + 1) : 0ull;
    R[5] = k2 ? wt(2, b + 2) : 0ull;
    R[6] = k2 ? wt(1, b + 2) : 0ull;
    R[7] = k3 ? wt(3, b + 3) : 0ull;
    R[8] = k3 ? wt(2, b + 3) : 0ull;
    R[9] = k3 ? wt(1, b + 3) : 0ull;
    #pragma unroll
    for (int m = 0; m < 4; ++m) {
      int c = b + 4 + m;
      bool ok = (c < VB);
      #pragma unroll
      for (int j = 0; j < 4; ++j)
        R[10 + m * 4 + j] = ok ? wt(4 + m - j, c) : 0ull;
    }
  };
  auto fixpoint = [&](u64 colw, u64 act) -> u64 {
    u64 U = act, K = 0;
    while (U) {
      u64 covered = __ballot((colw & U) != 0ull);
      u64 nk = U & ~covered;                     // definite keepers
      u64 supp = __ballot((colw & nk) != 0ull);  // definitely suppressed
      K |= nk;
      U &= ~(nk | supp);
    }
    return K;
  };

  u64 P0 = 0, P1 = 0, P2 = 0, P3 = 0;            // carry bank -> cols 4g..4g+3

  if (wave == 0 && NG > 0) load_w0(0, cur);

  for (int g = 0; g < NG; ++g) {
    // one barrier per iteration; LDS-only drain — global loads stay in flight
    asm volatile("s_waitcnt lgkmcnt(0)\ns_barrier" ::: "memory");

    if (wave == 0) {
      __builtin_amdgcn_s_setprio(1);             // favor the serial scan wave
      int b = 4 * g;
      u64 r0 = rem[b], r1 = rem[b + 1], r2 = rem[b + 2], r3 = rem[b + 3];
      // rotate double buffer; issue next group's 26 loads immediately
      if (g > 0) {
        #pragma unroll
        for (int i = 0; i < 26; ++i) cur[i] = nxt[i];
      }
      if (g + 1 < NG) load_w0(g + 1, nxt);

      int remn = n_valid - b * 64;
      u64 vm0, vm1, vm2, vm3;
      {
        int m0 = remn, m1 = remn - 64, m2 = remn - 128, m3 = remn - 192;
        vm0 = (m0 >= 64) ? ~0ull : ((m0 <= 0) ? 0ull : ((1ull << m0) - 1ull));
        vm1 = (m1 >= 64) ? ~0ull : ((m1 <= 0) ? 0ull : ((1ull << m1) - 1ull));
        vm2 = (m2 >= 64) ? ~0ull : ((m2 <= 0) ? 0ull : ((1ull << m2) - 1ull));
        vm3 = (m3 >= 64) ? ~0ull : ((m3 <= 0) ? 0ull : ((1ull << m3) - 1ull));
      }
      u64 act0 = vm0 & ~(rfl64(r0) | P0);
      u64 act1 = vm1 & ~(rfl64(r1) | P1);
      u64 act2 = vm2 & ~(rfl64(r2) | P2);
      u64 act3 = vm3 & ~(rfl64(r3) | P3);

      // ---- 4 sequential fixpoints with in-register coupling
      u64 kw0 = fixpoint(cur[0], act0);
      u64 s1 = __ballot((cur[4] & kw0) != 0ull);
      u64 kw1 = fixpoint(cur[1], act1 & ~s1);
      u64 s2 = __ballot(((cur[5] & kw0) | (cur[6] & kw1)) != 0ull);
      u64 kw2 = fixpoint(cur[2], act2 & ~s2);
      u64 s3 = __ballot(((cur[7] & kw0) | (cur[8] & kw1) | (cur[9] & kw2)) != 0ull);
      u64 kw3 = fixpoint(cur[3], act3 & ~s3);

      if (lane == 0) {
        keepw[b] = kw0; keepw[b + 1] = kw1;
        keepw[b + 2] = kw2; keepw[b + 3] = kw3;
      }

      // ---- carry bank: group g keepers -> cols 4g+4..4g+7 (4 ballots)
      P0 = __ballot(((cur[10] & kw0) | (cur[11] & kw1) |
                     (cur[12] & kw2) | (cur[13] & kw3)) != 0ull);
      P1 = __ballot(((cur[14] & kw0) | (cur[15] & kw1) |
                     (cur[16] & kw2) | (cur[17] & kw3)) != 0ull);
      P2 = __ballot(((cur[18] & kw0) | (cur[19] & kw1) |
                     (cur[20] & kw2) | (cur[21] & kw3)) != 0ull);
      P3 = __ballot(((cur[22] & kw0) | (cur[23] & kw1) |
                     (cur[24] & kw2) | (cur[25] & kw3)) != 0ull);
      __builtin_amdgcn_s_setprio(0);             // yield while others consume
    } else if (g >= 1) {
      // ---- same-iteration keeper-filtered consume of group e = g-1
      int e = g - 1;
      int base = 4 * e + 8;
      if (base < VB) {
        // keep-bit window for rows rs..rs+nr-1 of the 256-row group
        int wi = rs >> 6, sh = rs & 63;
        u64 lo = keepw[4 * e + wi];
        u64 hi = (sh + nr > 64 && wi < 3) ? keepw[4 * e + wi + 1] : 0ull;
        u64 window = sh ? ((lo >> sh) | (hi << (64 - sh))) : lo;
        window = rfl64(window);
        const u64* pr = mask + (u64)(256 * e + rs) * CBLK;
        int cL = base + lane;
        bool okL = (cL < VB);
        u64 acc = 0;
        #pragma unroll
        for (int r = 0; r < 37; ++r) {
          bool bit = (r < nr) && (((window >> r) & 1ull) != 0ull);
          u64 v = (bit && okL) ? pr[(u64)r * CBLK + cL] : 0ull;
          acc |= v;
        }
        if (okL && acc) atomicOr((unsigned long long*)&rem[cL], acc);
        if (base + 64 < VB) {                    // H half exists at all?
          int cH = cL + 64;
          bool okH = (cH < VB);
          u64 acc2 = 0;
          #pragma unroll
          for (int r = 0; r < 37; ++r) {
            bool bit = (r < nr) && (((window >> r) & 1ull) != 0ull);
            u64 v = (bit && okH) ? pr[(u64)r * CBLK + cH] : 0ull;
            acc2 |= v;
          }
          if (okH && acc2) atomicOr((unsigned long long*)&rem[cH], acc2);
        }
      }
    }
  }
  __syncthreads();

  // ---- fused masked output (512 threads)
  for (int r2 = tid; r2 < N_ANCH; r2 += 512) {
    u64 kv = keepw[r2 >> 6];
    bool kp = (kv >> (r2 & 63)) & 1ull;
    float4 b4 = sbox[r2];
    float sc = sscore[r2];
    float* o = out + r2 * 5;
    o[0] = kp ? b4.x : 0.f;
    o[1] = kp ? b4.y : 0.f;
    o[2] = kp ? b4.z : 0.f;
    o[3] = kp ? b4.w : 0.f;
    o[4] = kp ? sc : 0.f;
  }
}

extern "C" void kernel_launch(void* const* d_in, const int* in_sizes, int n_in,
                              void* d_out, int out_size, void* d_ws, size_t ws_size,
                              hipStream_t stream) {
  const float* raw = (const float*)d_in[0];
  float* out = (float*)d_out;
  char* ws = (char*)d_ws;
  // ws layout: sbox (8448*16 B) | sscore (8448*4 B) | mask (8400*132*8 B)
  //          | wlo_t (8*132*64*8 B)  ≈ 9.58 MB total
  float4* sbox = (float4*)ws;
  float* sscore = (float*)(ws + 8448 * 16);
  u64* mask = (u64*)(ws + 8448 * 16 + 8448 * 4);
  u64* wlo_t = (u64*)(ws + 8448 * 16 + 8448 * 4 + (size_t)N_ANCH * CBLK * 8);

  rank_kernel<<<525, 256, 0, stream>>>(raw, sbox, sscore);
  mask_kernel<<<dim3(CBLK, 33), 256, 0, stream>>>(sbox, sscore, mask, wlo_t);
  nms_kernel<<<1, 512, 0, stream>>>(sbox, sscore, mask, wlo_t, out);
}